// Round 1
// baseline (226.063 us; speedup 1.0000x reference)
//
#include <hip/hip_runtime.h>
#include <math.h>

#define BB 32
#define SS 1024
#define DD 256
#define ROWS 8
#define CHUNK 128

// Workspace layout (~320 KB total)
struct Ws {
  float sumall[BB][DD];    // per-batch column sums of embeddings
  float doorsum[BB][DD];   // per-batch column sums over door columns
  int   scount[BB];        // # switch rows per batch
  int   dcount[BB];        // # door cols per batch
  int   sidx[BB][SS];      // compacted switch row indices
  int   didx[BB][SS];      // compacted door col indices
};

__global__ void k_init(float* sums, int* counts) {
  int i = blockIdx.x * 256 + threadIdx.x;
  if (i < 2 * BB * DD) sums[i] = 0.0f;
  if (i < 2 * BB) counts[i] = 0;
}

__global__ void k_stats(const float* __restrict__ emb, const int* __restrict__ state, Ws* ws) {
  int b = blockIdx.x, c = blockIdx.y, tid = threadIdx.x;
  int s0 = c * CHUNK;
  const float* eb = emb + ((size_t)b * SS + s0) * DD;
  const int* stb = state + b * SS + s0;
  float acc = 0.f, accd = 0.f;
  for (int s = 0; s < CHUNK; ++s) {
    float v = eb[(size_t)s * DD + tid];
    int st = stb[s];
    acc += v;
    if (st == 4 || st == 5) accd += v;
  }
  atomicAdd(&ws->sumall[b][tid], acc);
  atomicAdd(&ws->doorsum[b][tid], accd);
  if (tid < CHUNK) {
    int st = stb[tid];
    int s = s0 + tid;
    if (st == 3) { int p = atomicAdd(&ws->scount[b], 1); ws->sidx[b][p] = s; }
    if (st == 4 || st == 5) { int p = atomicAdd(&ws->dcount[b], 1); ws->didx[b][p] = s; }
  }
}

// out = emb + 0.5 * mean_t(emb)  for every row (switch rows overwritten later)
__global__ void k_base(const float4* __restrict__ emb4, const float* __restrict__ sumall,
                       float4* __restrict__ out4) {
  int i = blockIdx.x * 256 + threadIdx.x;          // 0 .. B*S*D/4-1 = 2097151
  int b = i >> 16;                                  // S*D/4 = 65536 per batch
  int dg = i & (DD / 4 - 1);                        // 64 float4 groups per row
  float4 e = emb4[i];
  float4 m = *((const float4*)(sumall + (size_t)b * DD) + dg);
  const float k = 0.5f / SS;
  float4 o;
  o.x = e.x + k * m.x; o.y = e.y + k * m.y; o.z = e.z + k * m.z; o.w = e.w + k * m.w;
  out4[i] = o;
}

// Handles up to ROWS switch rows per block.
// score(s,t) = p_s . e_t + c_s   with p_s = Wk^T (Wq e_s + bq), c_s = q_s . bk
__global__ __launch_bounds__(256, 2)
void k_switch(const float* __restrict__ emb,
              const float* __restrict__ Wq, const float* __restrict__ bq,
              const float* __restrict__ Wk, const float* __restrict__ bk,
              const float* __restrict__ cwp,
              const Ws* __restrict__ ws, float* __restrict__ out) {
  __shared__ float E[ROWS][DD];   // switch-row embeddings
  __shared__ float Q[ROWS][DD];
  __shared__ float P[ROWS][DD];
  __shared__ float Z[ROWS][SS];   // logits then exp-weights over door cols
  __shared__ float red[256];
  __shared__ float c_s[ROWS], m_s[ROWS], den_s[ROWS];
  __shared__ int   srow[ROWS];
  __shared__ int   dlist[SS];

  int b = blockIdx.x, g = blockIdx.y, tid = threadIdx.x;
  int ns = ws->scount[b];
  int r0 = g * ROWS;
  if (r0 >= ns) return;
  int nr = min(ROWS, ns - r0);
  int nd = ws->dcount[b];

  if (tid < nr) srow[tid] = ws->sidx[b][r0 + tid];
  for (int j = tid; j < nd; j += 256) dlist[j] = ws->didx[b][j];
  __syncthreads();

  const float* eb = emb + (size_t)b * SS * DD;
  for (int r = 0; r < nr; ++r) E[r][tid] = eb[(size_t)srow[r] * DD + tid];
  __syncthreads();

  // Q[r][e] = Wq[e,:] . E[r] + bq[e]    (thread = output element e)
  {
    float acc[ROWS];
#pragma unroll
    for (int r = 0; r < ROWS; ++r) acc[r] = 0.f;
    const float* wq = Wq + (size_t)tid * DD;
    for (int d = 0; d < DD; ++d) {
      float w = wq[d];
#pragma unroll
      for (int r = 0; r < ROWS; ++r) acc[r] += w * E[r][d];
    }
    float bv = bq[tid];
#pragma unroll
    for (int r = 0; r < ROWS; ++r) Q[r][tid] = acc[r] + bv;
  }
  __syncthreads();

  // c_r = Q[r] . bk   (block tree reduction)
  float bkv = bk[tid];
  for (int r = 0; r < nr; ++r) {
    red[tid] = Q[r][tid] * bkv;
    __syncthreads();
    for (int o = 128; o > 0; o >>= 1) { if (tid < o) red[tid] += red[tid + o]; __syncthreads(); }
    if (tid == 0) c_s[r] = red[0];
    __syncthreads();
  }

  // P[r][d] = sum_e Q[r][e] * Wk[e,d]   (coalesced Wk reads)
  {
    float acc[ROWS];
#pragma unroll
    for (int r = 0; r < ROWS; ++r) acc[r] = 0.f;
    for (int e = 0; e < DD; ++e) {
      float w = Wk[(size_t)e * DD + tid];
#pragma unroll
      for (int r = 0; r < ROWS; ++r) acc[r] += Q[r][e] * w;
    }
#pragma unroll
    for (int r = 0; r < ROWS; ++r) P[r][tid] = acc[r];
  }
  __syncthreads();

  float cw = cwp[0];
  // logits for door columns: thread j handles one door column
  for (int j = tid; j < nd; j += 256) {
    const float* et = eb + (size_t)dlist[j] * DD;
    float acc[ROWS];
#pragma unroll
    for (int r = 0; r < ROWS; ++r) acc[r] = 0.f;
    for (int d = 0; d < DD; ++d) {
      float v = et[d];
#pragma unroll
      for (int r = 0; r < ROWS; ++r) acc[r] += P[r][d] * v;
    }
#pragma unroll
    for (int r = 0; r < ROWS; ++r) Z[r][j] = cw * (acc[r] + c_s[r]);
  }
  __syncthreads();

  // stable softmax stats; (S-nd) zero-logit entries handled in closed form
  for (int r = 0; r < nr; ++r) {
    float m = (nd < SS) ? 0.0f : -INFINITY;
    for (int j = tid; j < nd; j += 256) m = fmaxf(m, Z[r][j]);
    red[tid] = m; __syncthreads();
    for (int o = 128; o > 0; o >>= 1) { if (tid < o) red[tid] = fmaxf(red[tid], red[tid + o]); __syncthreads(); }
    m = red[0];
    __syncthreads();
    float s = 0.f;
    for (int j = tid; j < nd; j += 256) { float w = __expf(Z[r][j] - m); Z[r][j] = w; s += w; }
    red[tid] = s; __syncthreads();
    for (int o = 128; o > 0; o >>= 1) { if (tid < o) red[tid] += red[tid + o]; __syncthreads(); }
    if (tid == 0) { m_s[r] = m; den_s[r] = red[0] + (float)(SS - nd) * __expf(-m); }
    __syncthreads();
  }

  // weighted value sum over door columns (thread = d, coalesced emb rows)
  float acc[ROWS];
#pragma unroll
  for (int r = 0; r < ROWS; ++r) acc[r] = 0.f;
  for (int j = 0; j < nd; ++j) {
    float v = eb[(size_t)dlist[j] * DD + tid];
#pragma unroll
    for (int r = 0; r < ROWS; ++r) acc[r] += Z[r][j] * v;
  }
  float nondoor = ws->sumall[b][tid] - ws->doorsum[b][tid];
  for (int r = 0; r < nr; ++r) {
    float ce = (__expf(-m_s[r]) * nondoor + acc[r]) / den_s[r];
    out[((size_t)b * SS + srow[r]) * DD + tid] = E[r][tid] + 0.5f * ce;
  }
}

extern "C" void kernel_launch(void* const* d_in, const int* in_sizes, int n_in,
                              void* d_out, int out_size, void* d_ws, size_t ws_size,
                              hipStream_t stream) {
  const float* emb   = (const float*)d_in[0];
  const int*   state = (const int*)d_in[1];
  const float* Wq    = (const float*)d_in[2];
  const float* bq    = (const float*)d_in[3];
  const float* Wk    = (const float*)d_in[4];
  const float* bk    = (const float*)d_in[5];
  const float* cw    = (const float*)d_in[6];
  // causal_bias (d_in[7]) is mathematically irrelevant: softmax(x+c)==softmax(x)
  float* out = (float*)d_out;
  Ws* ws = (Ws*)d_ws;

  k_init<<<64, 256, 0, stream>>>((float*)ws, ws->scount);
  k_stats<<<dim3(BB, SS / CHUNK), 256, 0, stream>>>(emb, state, ws);
  k_base<<<(BB * SS * DD / 4) / 256, 256, 0, stream>>>((const float4*)emb,
                                                       (const float*)ws->sumall, (float4*)out);
  k_switch<<<dim3(BB, SS / ROWS), 256, 0, stream>>>(emb, Wq, bq, Wk, bk, cw, ws, out);
}

// Round 2
// 209.540 us; speedup vs baseline: 1.0789x; 1.0789x over previous
//
#include <hip/hip_runtime.h>
#include <math.h>

#define BB 32
#define SS 1024
#define DD 256
#define ROWS 8
#define CHUNK 128

// Workspace layout (~320 KB total)
struct Ws {
  float sumall[BB][DD];    // per-batch column sums of embeddings
  float doorsum[BB][DD];   // per-batch column sums over door columns
  int   scount[BB];        // # switch rows per batch
  int   dcount[BB];        // # door cols per batch
  int   sidx[BB][SS];      // compacted switch row indices
  int   didx[BB][SS];      // compacted door col indices
};

__global__ void k_init(float* sums, int* counts) {
  int i = blockIdx.x * 256 + threadIdx.x;
  if (i < 2 * BB * DD) sums[i] = 0.0f;
  if (i < 2 * BB) counts[i] = 0;
}

__global__ void k_stats(const float* __restrict__ emb, const int* __restrict__ state, Ws* ws) {
  int b = blockIdx.x, c = blockIdx.y, tid = threadIdx.x;
  int s0 = c * CHUNK;
  const float* eb = emb + ((size_t)b * SS + s0) * DD;
  const int* stb = state + b * SS + s0;
  float acc = 0.f, accd = 0.f;
  for (int s = 0; s < CHUNK; ++s) {
    float v = eb[(size_t)s * DD + tid];
    int st = stb[s];
    acc += v;
    if (st == 4 || st == 5) accd += v;
  }
  atomicAdd(&ws->sumall[b][tid], acc);
  atomicAdd(&ws->doorsum[b][tid], accd);
  if (tid < CHUNK) {
    int st = stb[tid];
    int s = s0 + tid;
    if (st == 3) { int p = atomicAdd(&ws->scount[b], 1); ws->sidx[b][p] = s; }
    if (st == 4 || st == 5) { int p = atomicAdd(&ws->dcount[b], 1); ws->didx[b][p] = s; }
  }
}

// out = emb + 0.5 * mean_t(emb)  for every row (switch rows overwritten later)
__global__ void k_base(const float4* __restrict__ emb4, const float* __restrict__ sumall,
                       float4* __restrict__ out4) {
  int i = blockIdx.x * 256 + threadIdx.x;          // 0 .. B*S*D/4-1
  int b = i >> 16;                                  // S*D/4 = 65536 per batch
  int dg = i & (DD / 4 - 1);
  float4 e = emb4[i];
  float4 m = *((const float4*)(sumall + (size_t)b * DD) + dg);
  const float k = 0.5f / SS;
  float4 o;
  o.x = e.x + k * m.x; o.y = e.y + k * m.y; o.z = e.z + k * m.z; o.w = e.w + k * m.w;
  out4[i] = o;
}

// Handles up to ROWS switch rows per block.
// score(s,t) = p_s . e_t + c_s   with p_s = Wk^T (Wq e_s + bq), c_s = q_s . bk
__global__ __launch_bounds__(256, 2)
void k_switch(const float* __restrict__ emb,
              const float* __restrict__ Wq, const float* __restrict__ bq,
              const float* __restrict__ Wk, const float* __restrict__ bk,
              const float* __restrict__ cwp,
              const Ws* __restrict__ ws, float* __restrict__ out) {
  __shared__ float E[ROWS][DD];
  __shared__ float Q[ROWS][DD];
  __shared__ float P[ROWS][DD];
  __shared__ float Z[ROWS][SS];
  __shared__ float wpart[4][ROWS];
  __shared__ float c_s[ROWS], m_s[ROWS], den_s[ROWS];
  __shared__ int   srow[ROWS];
  __shared__ int   dlist[SS];

  int b = blockIdx.x, g = blockIdx.y, tid = threadIdx.x;
  int lane = tid & 63, wid = tid >> 6;
  int ns = ws->scount[b];
  int r0 = g * ROWS;
  if (r0 >= ns) return;
  int nr = min(ROWS, ns - r0);
  int nd = ws->dcount[b];

  if (tid < ROWS) srow[tid] = ws->sidx[b][r0 + min(tid, nr - 1)];
  __syncthreads();                                   // srow ready
  const float* eb = emb + (size_t)b * SS * DD;
#pragma unroll
  for (int r = 0; r < ROWS; ++r) E[r][tid] = eb[(size_t)srow[r] * DD + tid];
  for (int j = tid; j < nd; j += 256) dlist[j] = ws->didx[b][j];
  __syncthreads();                                   // E, dlist ready

  // ---- Q[r][e] = Wq[e,:].E[r] + bq[e], and c_s[r] = Q[r].bk (wave reduce) ----
  {
    float acc[ROWS];
#pragma unroll
    for (int r = 0; r < ROWS; ++r) acc[r] = 0.f;
    const float4* wq4 = (const float4*)(Wq + (size_t)tid * DD);
    for (int d4 = 0; d4 < DD / 4; ++d4) {
      float4 w = wq4[d4];
#pragma unroll
      for (int r = 0; r < ROWS; ++r) {
        float4 e = ((const float4*)E[r])[d4];
        acc[r] += w.x * e.x + w.y * e.y + w.z * e.z + w.w * e.w;
      }
    }
    float bqv = bq[tid], bkv = bk[tid];
#pragma unroll
    for (int r = 0; r < ROWS; ++r) {
      float q = acc[r] + bqv;
      Q[r][tid] = q;
      float p = q * bkv;
#pragma unroll
      for (int off = 32; off > 0; off >>= 1) p += __shfl_down(p, off);
      if (lane == 0) wpart[wid][r] = p;
    }
  }
  __syncthreads();
  if (tid < ROWS) c_s[tid] = wpart[0][tid] + wpart[1][tid] + wpart[2][tid] + wpart[3][tid];
  __syncthreads();                                   // Q, c_s ready

  // ---- P[r][d] = sum_e Q[r][e] * Wk[e,d]  (coalesced Wk, b128 Q broadcast) ----
  {
    float acc[ROWS];
#pragma unroll
    for (int r = 0; r < ROWS; ++r) acc[r] = 0.f;
    for (int e4 = 0; e4 < DD / 4; ++e4) {
      int e = e4 * 4;
      float w0 = Wk[(size_t)(e + 0) * DD + tid];
      float w1 = Wk[(size_t)(e + 1) * DD + tid];
      float w2 = Wk[(size_t)(e + 2) * DD + tid];
      float w3 = Wk[(size_t)(e + 3) * DD + tid];
#pragma unroll
      for (int r = 0; r < ROWS; ++r) {
        float4 q = ((const float4*)Q[r])[e4];
        acc[r] += q.x * w0 + q.y * w1 + q.z * w2 + q.w * w3;
      }
    }
#pragma unroll
    for (int r = 0; r < ROWS; ++r) P[r][tid] = acc[r];
  }
  __syncthreads();                                   // P ready

  // ---- logits over door columns: thread = column, float4 emb reads ----
  float cw = cwp[0];
  for (int j = tid; j < nd; j += 256) {
    const float4* et4 = (const float4*)(eb + (size_t)dlist[j] * DD);
    float acc[ROWS];
#pragma unroll
    for (int r = 0; r < ROWS; ++r) acc[r] = 0.f;
    for (int d4 = 0; d4 < DD / 4; ++d4) {
      float4 v = et4[d4];
#pragma unroll
      for (int r = 0; r < ROWS; ++r) {
        float4 p = ((const float4*)P[r])[d4];
        acc[r] += p.x * v.x + p.y * v.y + p.z * v.z + p.w * v.w;
      }
    }
#pragma unroll
    for (int r = 0; r < ROWS; ++r) Z[r][j] = cw * (acc[r] + c_s[r]);
  }
  __syncthreads();                                   // Z (logits) ready

  // ---- softmax stats: wave w handles rows 2w, 2w+1; shuffle reductions ----
#pragma unroll
  for (int rr = 0; rr < 2; ++rr) {
    int r = wid * 2 + rr;
    float m = (nd < SS) ? 0.0f : -INFINITY;
    for (int j = lane; j < nd; j += 64) m = fmaxf(m, Z[r][j]);
#pragma unroll
    for (int off = 32; off > 0; off >>= 1) m = fmaxf(m, __shfl_down(m, off));
    m = __shfl(m, 0);
    float s = 0.f;
    for (int j = lane; j < nd; j += 64) { float w = __expf(Z[r][j] - m); Z[r][j] = w; s += w; }
#pragma unroll
    for (int off = 32; off > 0; off >>= 1) s += __shfl_down(s, off);
    if (lane == 0) { m_s[r] = m; den_s[r] = s + (float)(SS - nd) * __expf(-m); }
  }
  __syncthreads();                                   // Z (weights), m_s, den_s ready

  // ---- weighted value sum over door columns (thread = d), j unrolled x4 ----
  float acc[ROWS];
#pragma unroll
  for (int r = 0; r < ROWS; ++r) acc[r] = 0.f;
  int j4 = nd & ~3;
  for (int j = 0; j < j4; j += 4) {
    float v0 = eb[(size_t)dlist[j + 0] * DD + tid];
    float v1 = eb[(size_t)dlist[j + 1] * DD + tid];
    float v2 = eb[(size_t)dlist[j + 2] * DD + tid];
    float v3 = eb[(size_t)dlist[j + 3] * DD + tid];
#pragma unroll
    for (int r = 0; r < ROWS; ++r) {
      float4 z = *(const float4*)&Z[r][j];
      acc[r] += z.x * v0 + z.y * v1 + z.z * v2 + z.w * v3;
    }
  }
  for (int j = j4; j < nd; ++j) {
    float v = eb[(size_t)dlist[j] * DD + tid];
#pragma unroll
    for (int r = 0; r < ROWS; ++r) acc[r] += Z[r][j] * v;
  }

  float nondoor = ws->sumall[b][tid] - ws->doorsum[b][tid];
  for (int r = 0; r < nr; ++r) {
    float ce = (__expf(-m_s[r]) * nondoor + acc[r]) / den_s[r];
    out[((size_t)b * SS + srow[r]) * DD + tid] = E[r][tid] + 0.5f * ce;
  }
}

extern "C" void kernel_launch(void* const* d_in, const int* in_sizes, int n_in,
                              void* d_out, int out_size, void* d_ws, size_t ws_size,
                              hipStream_t stream) {
  const float* emb   = (const float*)d_in[0];
  const int*   state = (const int*)d_in[1];
  const float* Wq    = (const float*)d_in[2];
  const float* bq    = (const float*)d_in[3];
  const float* Wk    = (const float*)d_in[4];
  const float* bk    = (const float*)d_in[5];
  const float* cw    = (const float*)d_in[6];
  // causal_bias (d_in[7]) is mathematically irrelevant: softmax(x+c)==softmax(x)
  float* out = (float*)d_out;
  Ws* ws = (Ws*)d_ws;

  k_init<<<64, 256, 0, stream>>>((float*)ws, ws->scount);
  k_stats<<<dim3(BB, SS / CHUNK), 256, 0, stream>>>(emb, state, ws);
  k_base<<<(BB * SS * DD / 4) / 256, 256, 0, stream>>>((const float4*)emb,
                                                       (const float*)ws->sumall, (float4*)out);
  k_switch<<<dim3(BB, SS / ROWS), 256, 0, stream>>>(emb, Wq, bq, Wk, bk, cw, ws, out);
}